// Round 6
// baseline (135.259 us; speedup 1.0000x reference)
//
#include <hip/hip_runtime.h>
#include <hip/hip_bf16.h>

typedef short bf16x8 __attribute__((ext_vector_type(8)));
typedef float f32x4 __attribute__((ext_vector_type(4)));
typedef unsigned int u32;
typedef u32 u32x4 __attribute__((ext_vector_type(4)));

#define T_SEQ 2048
#define NB 8
#define NEGB (-1e30f)

__device__ inline unsigned short f2bf(float f) {
  unsigned u = __builtin_bit_cast(unsigned, f);
  u += 0x7FFFu + ((u >> 16) & 1u);   // round-to-nearest-even
  return (unsigned short)(u >> 16);
}
__device__ inline float bf2f(unsigned short h) {
  unsigned u = ((unsigned)h) << 16;
  return __builtin_bit_cast(float, u);
}
__device__ inline u32 cvt2(float a, float b) {  // v_cvt_pk_bf16_f32 via HIP
  __hip_bfloat162 h = __float22bfloat162_rn(make_float2(a, b));
  u32 r;
  __builtin_memcpy(&r, &h, 4);
  return r;
}
__device__ inline bf16x8 packfrag(float4 lo, float4 hi) {
  u32x4 p;
  p[0] = cvt2(lo.x, lo.y);
  p[1] = cvt2(lo.z, lo.w);
  p[2] = cvt2(hi.x, hi.y);
  p[3] = cvt2(hi.z, hi.w);
  return __builtin_bit_cast(bf16x8, p);
}
__device__ inline f32x4 mfma16(bf16x8 a, bf16x8 b, f32x4 c) {
  return __builtin_amdgcn_mfma_f32_16x16x32_bf16(a, b, c, 0, 0, 0);
}

// ---- pad_mask dtype detection: bool(1B) vs int32(4B) storage -------------
__global__ void detect_k(const unsigned char* m, int* flag) {
  __shared__ int ones, bad;
  int tid = threadIdx.x;
  if (tid == 0) { ones = 0; bad = 0; }
  __syncthreads();
  int lo = 0, lb = 0;
  for (int i = tid; i < NB * T_SEQ; i += 256) {
    int v = (m[i] != 0);
    lo += v;
    if (i & 3) lb += v;
  }
  atomicAdd(&ones, lo);
  atomicAdd(&bad, lb);
  __syncthreads();
  if (tid == 0) *flag = (ones > 0 && bad == 0) ? 1 : 0;
}

__global__ void lengths_k(const unsigned char* m, const int* flag, int* lengths) {
  int b = blockIdx.x, tid = threadIdx.x;
  int cnt = 0;
  if (*flag) {
    const int* mi = (const int*)m;
    for (int t = tid; t < T_SEQ; t += 256) cnt += (mi[b * T_SEQ + t] == 0);
  } else {
    for (int t = tid; t < T_SEQ; t += 256) cnt += (m[b * T_SEQ + t] == 0);
  }
  for (int off = 32; off >= 1; off >>= 1) cnt += __shfl_xor(cnt, off);
  __shared__ int wsum[4];
  if ((tid & 63) == 0) wsum[tid >> 6] = cnt;
  __syncthreads();
  if (tid == 0) lengths[b] = wsum[0] + wsum[1] + wsum[2] + wsum[3];
}

// WT[mi][n][k] (bf16) = W_mi[k][n]
__global__ void wt_k(const float* Wq, const float* Wk, const float* Wv,
                     unsigned short* wt) {
  int e = blockIdx.x * 256 + threadIdx.x;
  if (e >= 3 * 64 * 1024) return;
  int mi = e >> 16;
  int rem = e & 65535;
  int kk = rem & 1023, n = rem >> 10;
  const float* W = (mi == 0) ? Wq : (mi == 1) ? Wk : Wv;
  wt[e] = f2bf(W[kk * 64 + n]);
}

// Projection GEMM v5: barrier-free streaming, direct per-lane A-frag loads
// (v1-proven addressing), 4-wave k-split, 2-chunk register pipeline,
// packed cvt. One LDS reduce + one barrier per 16-row tile.
__global__ __launch_bounds__(256, 3) void proj_k(
    const float* Q, const float* K, const float* V, const unsigned short* wt,
    unsigned short* qo, unsigned short* ko, unsigned short* vTb) {
  __shared__ f32x4 red[3][4][64];
  int mi = blockIdx.y;
  const float* X = (mi == 0) ? Q : (mi == 1) ? K : V;
  const unsigned short* wtm = wt + mi * 65536;
  int tid = threadIdx.x;
  int w = tid >> 6, lane = tid & 63, l15 = lane & 15, g = lane >> 4;
  int tile = blockIdx.x;
  int kw0 = w * 256;  // this wave's k-slice
  // A-frag source: row = l15, k = kw0 + c*64 + ks*32 + g*8  (direct, no shfl)
  const float* xrow = X + (size_t)(tile * 16 + l15) * 1024 + kw0 + g * 8;

  f32x4 acc[4];
#pragma unroll
  for (int i = 0; i < 4; ++i) acc[i] = 0;

  float4 xA0, xA1, xA2, xA3, xB0, xB1, xB2, xB3;
  bf16x8 bA0, bA1, bA2, bA3, bA4, bA5, bA6, bA7;
  bf16x8 bB0, bB1, bB2, bB3, bB4, bB5, bB6, bB7;

  // ks0 frag = (p0,p1) at k offset c*64; ks1 frag = (p2,p3) at +32
#define LOADX(p0, p1, p2, p3, c)                  \
  do {                                            \
    const float* xp = xrow + (c) * 64;            \
    p0 = *(const float4*)(xp);                    \
    p1 = *(const float4*)(xp + 4);                \
    p2 = *(const float4*)(xp + 32);               \
    p3 = *(const float4*)(xp + 36);               \
  } while (0)
  // W frag (ks,nt) at n=nt*16+l15, k=kw0+c*64+ks*32+g*8
#define LOADW(q0, q1, q2, q3, q4, q5, q6, q7, c)                            \
  do {                                                                      \
    const unsigned short* wp0 = wtm + (size_t)(l15)*1024 + kw0 + (c)*64 + g * 8; \
    q0 = *(const bf16x8*)(wp0);                                             \
    q1 = *(const bf16x8*)(wp0 + 32);                                        \
    q2 = *(const bf16x8*)(wp0 + 16384);                                     \
    q3 = *(const bf16x8*)(wp0 + 16384 + 32);                                \
    q4 = *(const bf16x8*)(wp0 + 32768);                                     \
    q5 = *(const bf16x8*)(wp0 + 32768 + 32);                                \
    q6 = *(const bf16x8*)(wp0 + 49152);                                     \
    q7 = *(const bf16x8*)(wp0 + 49152 + 32);                                \
  } while (0)
#define COMPUTE(f0, f1, f2, f3, w0, w1, w2, w3, w4, w5, w6, w7)  \
  do {                                                           \
    bf16x8 afr = packfrag(f0, f1); /* ks=0 */                    \
    acc[0] = mfma16(afr, w0, acc[0]);                            \
    acc[1] = mfma16(afr, w2, acc[1]);                            \
    acc[2] = mfma16(afr, w4, acc[2]);                            \
    acc[3] = mfma16(afr, w6, acc[3]);                            \
    afr = packfrag(f2, f3); /* ks=1 */                           \
    acc[0] = mfma16(afr, w1, acc[0]);                            \
    acc[1] = mfma16(afr, w3, acc[1]);                            \
    acc[2] = mfma16(afr, w5, acc[2]);                            \
    acc[3] = mfma16(afr, w7, acc[3]);                            \
  } while (0)

  // software pipeline: chunk c+1 loads issued before computing chunk c
  LOADX(xA0, xA1, xA2, xA3, 0);
  LOADW(bA0, bA1, bA2, bA3, bA4, bA5, bA6, bA7, 0);
  LOADX(xB0, xB1, xB2, xB3, 1);
  LOADW(bB0, bB1, bB2, bB3, bB4, bB5, bB6, bB7, 1);
  COMPUTE(xA0, xA1, xA2, xA3, bA0, bA1, bA2, bA3, bA4, bA5, bA6, bA7);
  LOADX(xA0, xA1, xA2, xA3, 2);
  LOADW(bA0, bA1, bA2, bA3, bA4, bA5, bA6, bA7, 2);
  COMPUTE(xB0, xB1, xB2, xB3, bB0, bB1, bB2, bB3, bB4, bB5, bB6, bB7);
  LOADX(xB0, xB1, xB2, xB3, 3);
  LOADW(bB0, bB1, bB2, bB3, bB4, bB5, bB6, bB7, 3);
  COMPUTE(xA0, xA1, xA2, xA3, bA0, bA1, bA2, bA3, bA4, bA5, bA6, bA7);
  COMPUTE(xB0, xB1, xB2, xB3, bB0, bB1, bB2, bB3, bB4, bB5, bB6, bB7);
#undef COMPUTE
#undef LOADW
#undef LOADX

  // k-split reduce across the 4 waves (one barrier per tile)
  if (w > 0) {
#pragma unroll
    for (int nt = 0; nt < 4; ++nt) red[w - 1][nt][lane] = acc[nt];
  }
  __syncthreads();
  if (w == 0) {
#pragma unroll
    for (int nt = 0; nt < 4; ++nt) {
      f32x4 s = acc[nt];
      s += red[0][nt][lane];
      s += red[1][nt][lane];
      s += red[2][nt][lane];
#pragma unroll
      for (int vv = 0; vv < 4; ++vv) {
        int rr = tile * 16 + g * 4 + vv;   // D layout: row = g*4+vv
        int c = nt * 16 + l15;             //            col = lane&15
        float val = s[vv];
        if (mi == 0) {
          qo[(size_t)rr * 64 + c] = f2bf(val * 0.03125f);  // fold C^-0.5
        } else if (mi == 1) {
          ko[(size_t)rr * 64 + c] = f2bf(val);
        } else {
          int bb = rr >> 11, ts = rr & 2047;
          // tile-blocked vT: [b][t/32][d][t%32]
          vTb[(((size_t)bb * 64 + (ts >> 5)) * 64 + c) * 32 + (ts & 31)] =
              f2bf(val);
        }
      }
    }
  }
}

// vmean[b][d] from tile-blocked vT
__global__ void vmean_k(const unsigned short* vTb, float* vmean) {
  int b = blockIdx.x, tid = threadIdx.x;
  int k8 = tid & 3;
  int d = tid >> 2;
  const unsigned short* base = vTb + (size_t)b * 131072;
  float s = 0.f;
  for (int tt = 0; tt < 64; ++tt) {
    bf16x8 v = *(const bf16x8*)&base[(tt * 64 + d) * 32 + k8 * 8];
#pragma unroll
    for (int i = 0; i < 8; ++i) s += bf2f((unsigned short)v[i]);
  }
  s += __shfl_xor(s, 1);
  s += __shfl_xor(s, 2);
  if (k8 == 0) vmean[b * 64 + d] = s * (1.0f / T_SEQ);
}

// Flash attention: 512 threads = 8 waves = 4 key-chunks x 2 row-groups;
// 32 q-rows per block; 512 blocks (2/CU) with work-complementary swizzle.
__global__ __launch_bounds__(512, 4) void attn_k(
    const unsigned short* q, const unsigned short* k, const unsigned short* vTb,
    const float* vmean, const int* lengths, float* Out) {
  __shared__ unsigned short pL[8][16][40];      // per-wave P round-trip
  __shared__ unsigned short oP[4][2][16][64];   // bf16 partial O [j][r][row][col]
  __shared__ float mP[4][2][16], lP[4][2][16];

  // complementary work pairing: co-resident blocks sum to ~constant work
  int id = blockIdx.x;
  int raw = id & 63, b = id >> 6;
  int xx = (raw + 8 * b) & 63;
  int tile = (xx < 32) ? xx : 95 - xx;   // bijective on 0..63
  int t0 = tile * 32;

  int tid = threadIdx.x;
  int w = tid >> 6, lane = tid & 63;
  int j = w >> 1, r = w & 1;
  int l15 = lane & 15, g = lane >> 4;
  int t_base = t0 + r * 16;

  const bf16x8* qrow =
      (const bf16x8*)(q + ((size_t)b * T_SEQ + t_base + l15) * 64);
  bf16x8 aq0 = qrow[g];
  bf16x8 aq1 = qrow[4 + g];

  f32x4 o[4];
  float m[4], l[4];
#pragma unroll
  for (int i = 0; i < 4; ++i) { o[i] = 0; m[i] = NEGB; l[i] = 0.f; }

  const bf16x8* kch = (const bf16x8*)k + (size_t)b * T_SEQ * 8;
  const unsigned short* vch = vTb + (size_t)b * 131072;

  // balanced contiguous tile-chunks over this block's NT key-tiles
  int NT = tile + 1;
  int qn = NT >> 2, rem = NT & 3;
  int start = j * qn + (j < rem ? j : rem);
  int end = start + qn + (j < rem ? 1 : 0);
  int capw = ((t_base + 15) >> 5) + 1;
  if (end > capw) end = capw;

  for (int tt = start; tt < end; ++tt) {
    int s0 = tt * 32;
    f32x4 sa0, sa1;
    sa0 = 0; sa1 = 0;
    bf16x8 kb00 = kch[(size_t)(s0 + l15) * 8 + g];
    bf16x8 kb01 = kch[(size_t)(s0 + l15) * 8 + 4 + g];
    bf16x8 kb10 = kch[(size_t)(s0 + 16 + l15) * 8 + g];
    bf16x8 kb11 = kch[(size_t)(s0 + 16 + l15) * 8 + 4 + g];
    sa0 = mfma16(aq0, kb00, sa0);
    sa0 = mfma16(aq1, kb01, sa0);
    sa1 = mfma16(aq0, kb10, sa1);
    sa1 = mfma16(aq1, kb11, sa1);
#pragma unroll
    for (int vv = 0; vv < 4; ++vv) {
      int t = t_base + g * 4 + vv;
      float v0 = (s0 + l15 <= t) ? sa0[vv] : NEGB;
      float v1 = (s0 + 16 + l15 <= t) ? sa1[vv] : NEGB;
      float rm = fmaxf(v0, v1);
#pragma unroll
      for (int off = 8; off >= 1; off >>= 1)
        rm = fmaxf(rm, __shfl_xor(rm, off));
      float mn = fmaxf(m[vv], rm);
      float corr = __expf(m[vv] - mn);
      float p0 = (v0 == NEGB) ? 0.f : __expf(v0 - mn);  // all-masked tile guard
      float p1 = (v1 == NEGB) ? 0.f : __expf(v1 - mn);
      float rs = p0 + p1;
#pragma unroll
      for (int off = 8; off >= 1; off >>= 1) rs += __shfl_xor(rs, off);
      l[vv] = l[vv] * corr + rs;
      m[vv] = mn;
#pragma unroll
      for (int nt = 0; nt < 4; ++nt) o[nt][vv] *= corr;
      pL[w][g * 4 + vv][l15] = f2bf(p0);
      pL[w][g * 4 + vv][16 + l15] = f2bf(p1);
    }
    bf16x8 ap = *(const bf16x8*)&pL[w][l15][g * 8];
#pragma unroll
    for (int nt = 0; nt < 4; ++nt) {
      bf16x8 bv =
          *(const bf16x8*)&vch[((size_t)(tt * 64 + nt * 16 + l15)) * 32 + g * 8];
      o[nt] = mfma16(ap, bv, o[nt]);
    }
  }

  __syncthreads();
#pragma unroll
  for (int nt = 0; nt < 4; ++nt)
#pragma unroll
    for (int vv = 0; vv < 4; ++vv)
      oP[j][r][g * 4 + vv][nt * 16 + l15] = f2bf(o[nt][vv]);
  if (l15 == 0) {
#pragma unroll
    for (int vv = 0; vv < 4; ++vv) {
      mP[j][r][g * 4 + vv] = m[vv];
      lP[j][r][g * 4 + vv] = l[vv];
    }
  }
  __syncthreads();

  if (w < 2) {  // merge wave r=w: 16 rows x 64 cols, 4-way j-merge
    int len = lengths[b];
#pragma unroll 4
    for (int row = 0; row < 16; ++row) {
      float m0 = mP[0][w][row], m1 = mP[1][w][row];
      float m2 = mP[2][w][row], m3 = mP[3][w][row];
      float ms = fmaxf(fmaxf(m0, m1), fmaxf(m2, m3));
      float e0 = __expf(m0 - ms), e1 = __expf(m1 - ms);
      float e2 = __expf(m2 - ms), e3 = __expf(m3 - ms);
      float ls = lP[0][w][row] * e0 + lP[1][w][row] * e1 +
                 lP[2][w][row] * e2 + lP[3][w][row] * e3;
      float ov = bf2f(oP[0][w][row][lane]) * e0 +
                 bf2f(oP[1][w][row][lane]) * e1 +
                 bf2f(oP[2][w][row][lane]) * e2 +
                 bf2f(oP[3][w][row][lane]) * e3;
      float val = ov / ls;
      int t = t0 + w * 16 + row;
      if (t >= len) val = vmean[b * 64 + lane];  // padded query row -> mean(v)
      Out[((size_t)b * T_SEQ + t) * 64 + lane] = val;
    }
  }
}

extern "C" void kernel_launch(void* const* d_in, const int* in_sizes, int n_in,
                              void* d_out, int out_size, void* d_ws,
                              size_t ws_size, hipStream_t stream) {
  const float* V = (const float*)d_in[0];
  const float* K = (const float*)d_in[1];
  const float* Q = (const float*)d_in[2];
  const float* Wq = (const float*)d_in[3];
  const float* Wk = (const float*)d_in[4];
  const float* Wv = (const float*)d_in[5];
  const unsigned char* mask = (const unsigned char*)d_in[6];
  float* O = (float*)d_out;
  char* ws = (char*)d_ws;

  unsigned short* wt = (unsigned short*)(ws);                        // 384 KiB
  unsigned short* qb = (unsigned short*)(ws + 393216);               // 2 MiB
  unsigned short* kb = (unsigned short*)(ws + 393216 + 2097152);     // 2 MiB
  unsigned short* vTb = (unsigned short*)(ws + 393216 + 2 * 2097152);// 2 MiB
  float* vmean = (float*)(ws + 393216 + 3 * 2097152);                // 2 KiB
  int* lengths = (int*)(ws + 393216 + 3 * 2097152 + 2048);
  int* flag = lengths + 8;

  detect_k<<<1, 256, 0, stream>>>(mask, flag);
  lengths_k<<<NB, 256, 0, stream>>>(mask, flag, lengths);
  wt_k<<<768, 256, 0, stream>>>(Wq, Wk, Wv, wt);
  proj_k<<<dim3(1024, 3), 256, 0, stream>>>(Q, K, V, wt, qb, kb, vTb);
  vmean_k<<<NB, 256, 0, stream>>>(vTb, vmean);
  attn_k<<<512, 512, 0, stream>>>(qb, kb, vTb, vmean, lengths, O);
}

// Round 7
// 100.587 us; speedup vs baseline: 1.3447x; 1.3447x over previous
//
#include <hip/hip_runtime.h>
#include <hip/hip_bf16.h>

typedef short bf16x8 __attribute__((ext_vector_type(8)));
typedef float f32x4 __attribute__((ext_vector_type(4)));
typedef unsigned int u32;
typedef u32 u32x4 __attribute__((ext_vector_type(4)));

#define T_SEQ 2048
#define NB 8
#define NEGB (-1e30f)

__device__ inline unsigned short f2bf(float f) {
  unsigned u = __builtin_bit_cast(unsigned, f);
  u += 0x7FFFu + ((u >> 16) & 1u);   // round-to-nearest-even
  return (unsigned short)(u >> 16);
}
__device__ inline float bf2f(unsigned short h) {
  unsigned u = ((unsigned)h) << 16;
  return __builtin_bit_cast(float, u);
}
__device__ inline u32 cvt2(float a, float b) {  // v_cvt_pk_bf16_f32 via HIP
  __hip_bfloat162 h = __float22bfloat162_rn(make_float2(a, b));
  u32 r;
  __builtin_memcpy(&r, &h, 4);
  return r;
}
__device__ inline bf16x8 pack8(float4 a, float4 b) {
  u32x4 p;
  p[0] = cvt2(a.x, a.y);
  p[1] = cvt2(a.z, a.w);
  p[2] = cvt2(b.x, b.y);
  p[3] = cvt2(b.z, b.w);
  return __builtin_bit_cast(bf16x8, p);
}
__device__ inline f32x4 mfma16(bf16x8 a, bf16x8 b, f32x4 c) {
  return __builtin_amdgcn_mfma_f32_16x16x32_bf16(a, b, c, 0, 0, 0);
}
// async 16B global -> LDS (DMA). ldsptr wave-uniform; lane l lands at +l*16.
__device__ __forceinline__ void gl_lds16(const void* g, void* l) {
  __builtin_amdgcn_global_load_lds(
      (const __attribute__((address_space(1))) void*)g,
      (__attribute__((address_space(3))) void*)l, 16, 0, 0);
}

// ---- pad_mask dtype detection: bool(1B) vs int32(4B) storage -------------
__global__ void detect_k(const unsigned char* m, int* flag) {
  __shared__ int ones, bad;
  int tid = threadIdx.x;
  if (tid == 0) { ones = 0; bad = 0; }
  __syncthreads();
  int lo = 0, lb = 0;
  for (int i = tid; i < NB * T_SEQ; i += 256) {
    int v = (m[i] != 0);
    lo += v;
    if (i & 3) lb += v;
  }
  atomicAdd(&ones, lo);
  atomicAdd(&bad, lb);
  __syncthreads();
  if (tid == 0) *flag = (ones > 0 && bad == 0) ? 1 : 0;
}

__global__ void lengths_k(const unsigned char* m, const int* flag, int* lengths) {
  int b = blockIdx.x, tid = threadIdx.x;
  int cnt = 0;
  if (*flag) {
    const int* mi = (const int*)m;
    for (int t = tid; t < T_SEQ; t += 256) cnt += (mi[b * T_SEQ + t] == 0);
  } else {
    for (int t = tid; t < T_SEQ; t += 256) cnt += (m[b * T_SEQ + t] == 0);
  }
  for (int off = 32; off >= 1; off >>= 1) cnt += __shfl_xor(cnt, off);
  __shared__ int wsum[4];
  if ((tid & 63) == 0) wsum[tid >> 6] = cnt;
  __syncthreads();
  if (tid == 0) lengths[b] = wsum[0] + wsum[1] + wsum[2] + wsum[3];
}

// WT[mi][n][k] (bf16) = W_mi[k][n]
__global__ void wt_k(const float* Wq, const float* Wk, const float* Wv,
                     unsigned short* wt) {
  int e = blockIdx.x * 256 + threadIdx.x;
  if (e >= 3 * 64 * 1024) return;
  int mi = e >> 16;
  int rem = e & 65535;
  int kk = rem & 1023, n = rem >> 10;
  const float* W = (mi == 0) ? Wq : (mi == 1) ? Wk : Wv;
  wt[e] = f2bf(W[kk * 64 + n]);
}

// Projection GEMM v6 = R3's proven structure + T4 counted-vmcnt:
// loads for chunk kc+1 stay in flight across BOTH barriers (never drain to 0).
// Schedule/iter: STAGE(kc+1) -> vmcnt(3) -> bar -> compute(kc) -> lgkm(0) -> bar
__global__ __launch_bounds__(512, 4) void proj_k(
    const float* Q, const float* K, const float* V, const unsigned short* wt,
    unsigned short* qo, unsigned short* ko, unsigned short* vTb) {
  __shared__ float xs[2][4096];          // 16 KB x2: [row][k] f32 (pre-swizzled)
  __shared__ unsigned short wss[2][4096];// 8 KB x2: [n][k] bf16 (pre-swizzled)
  int mi = blockIdx.y;
  const float* X = (mi == 0) ? Q : (mi == 1) ? K : V;
  const unsigned short* wtm = wt + mi * 65536;
  int tid = threadIdx.x;
  int w = tid >> 6, lane = tid & 63, l15 = lane & 15, g = lane >> 4;
  int wr = w >> 1, wc = w & 1;
  int r0b = blockIdx.x * 64;

  // staging addresses (R3-verified): per wave exactly 3 gl_lds instrs/chunk
  int segA = w * 2;
  int rowA0 = segA * 4 + (lane >> 4);
  int rowA1 = rowA0 + 4;
  int colA0 = ((lane & 15) ^ (rowA0 & 15)) * 4;
  int colA1 = ((lane & 15) ^ (rowA1 & 15)) * 4;
  const float* srcA0 = X + (size_t)(r0b + rowA0) * 1024 + colA0;
  const float* srcA1 = X + (size_t)(r0b + rowA1) * 1024 + colA1;
  int nW = w * 8 + (lane >> 3);
  int skW = ((lane & 7) ^ (nW & 7)) * 8;
  const unsigned short* srcW = wtm + (size_t)nW * 1024 + skW;

  f32x4 acc[2];
  acc[0] = 0; acc[1] = 0;

#define STAGE(buf, kc2)                                          \
  do {                                                           \
    gl_lds16(srcA0 + (kc2) * 64, &xs[buf][segA * 256]);          \
    gl_lds16(srcA1 + (kc2) * 64, &xs[buf][segA * 256 + 256]);    \
    gl_lds16(srcW + (kc2) * 64, &wss[buf][w * 512]);             \
  } while (0)

  STAGE(0, 0);  // prologue: chunk 0 in flight

  int arow = wr * 16 + l15;
  for (int kc = 0; kc < 16; ++kc) {
    int cur = kc & 1;
    if (kc < 15) {
      STAGE(cur ^ 1, kc + 1);  // overwrite-safe: post-compute barrier of kc-1
      // wait chunk kc only; chunk kc+1's 3 loads REMAIN IN FLIGHT (T4)
      asm volatile("s_waitcnt vmcnt(3)" ::: "memory");
    } else {
      asm volatile("s_waitcnt vmcnt(0)" ::: "memory");
    }
    __builtin_amdgcn_s_barrier();  // raw: no compiler vmcnt(0) drain
#pragma unroll
    for (int ks = 0; ks < 2; ++ks) {
      int lb0 = ks * 8 + g * 2;
      float4 fa = *(const float4*)&xs[cur][arow * 64 + ((lb0 ^ l15) * 4)];
      float4 fb = *(const float4*)&xs[cur][arow * 64 + (((lb0 + 1) ^ l15) * 4)];
      bf16x8 a = pack8(fa, fb);
#pragma unroll
      for (int nt = 0; nt < 2; ++nt) {
        int nrow = wc * 32 + nt * 16 + l15;
        bf16x8 bb = *(const bf16x8*)
            &wss[cur][nrow * 64 + (((ks * 4 + g) ^ (l15 & 7)) * 8)];
        acc[nt] = mfma16(a, bb, acc[nt]);
      }
    }
    if (kc < 15) {
      // my LDS reads must retire before others' next STAGE overwrites
      asm volatile("s_waitcnt lgkmcnt(0)" ::: "memory");
      __builtin_amdgcn_s_barrier();
    }
  }
#undef STAGE

  // D layout: col = lane&15, row = g*4 + vv
#pragma unroll
  for (int nt = 0; nt < 2; ++nt)
#pragma unroll
    for (int vv = 0; vv < 4; ++vv) {
      int rr = r0b + wr * 16 + g * 4 + vv;
      int c = wc * 32 + nt * 16 + l15;
      float val = acc[nt][vv];
      if (mi == 0) {
        qo[(size_t)rr * 64 + c] = f2bf(val * 0.03125f);  // fold C^-0.5
      } else if (mi == 1) {
        ko[(size_t)rr * 64 + c] = f2bf(val);
      } else {
        int bb = rr >> 11, ts = rr & 2047;
        // tile-blocked vT: [b][t/32][d][t%32]
        vTb[(((size_t)bb * 64 + (ts >> 5)) * 64 + c) * 32 + (ts & 31)] =
            f2bf(val);
      }
    }
}

// vmean[b][d] from tile-blocked vT
__global__ void vmean_k(const unsigned short* vTb, float* vmean) {
  int b = blockIdx.x, tid = threadIdx.x;
  int k8 = tid & 3;
  int d = tid >> 2;
  const unsigned short* base = vTb + (size_t)b * 131072;
  float s = 0.f;
  for (int tt = 0; tt < 64; ++tt) {
    bf16x8 v = *(const bf16x8*)&base[(tt * 64 + d) * 32 + k8 * 8];
#pragma unroll
    for (int i = 0; i < 8; ++i) s += bf2f((unsigned short)v[i]);
  }
  s += __shfl_xor(s, 1);
  s += __shfl_xor(s, 2);
  if (k8 == 0) vmean[b * 64 + d] = s * (1.0f / T_SEQ);
}

// Flash attention: 512 threads = 8 waves = 4 key-chunks x 2 row-groups;
// 32 q-rows per block; 512 blocks (2/CU) with work-complementary swizzle.
__global__ __launch_bounds__(512, 4) void attn_k(
    const unsigned short* q, const unsigned short* k, const unsigned short* vTb,
    const float* vmean, const int* lengths, float* Out) {
  __shared__ unsigned short pL[8][16][40];      // per-wave P round-trip
  __shared__ unsigned short oP[4][2][16][64];   // bf16 partial O [j][r][row][col]
  __shared__ float mP[4][2][16], lP[4][2][16];

  // complementary work pairing: co-resident blocks sum to ~constant work
  int id = blockIdx.x;
  int raw = id & 63, b = id >> 6;
  int xx = (raw + 8 * b) & 63;
  int tile = (xx < 32) ? xx : 95 - xx;   // bijective on 0..63
  int t0 = tile * 32;

  int tid = threadIdx.x;
  int w = tid >> 6, lane = tid & 63;
  int j = w >> 1, r = w & 1;
  int l15 = lane & 15, g = lane >> 4;
  int t_base = t0 + r * 16;

  const bf16x8* qrow =
      (const bf16x8*)(q + ((size_t)b * T_SEQ + t_base + l15) * 64);
  bf16x8 aq0 = qrow[g];
  bf16x8 aq1 = qrow[4 + g];

  f32x4 o[4];
  float m[4], l[4];
#pragma unroll
  for (int i = 0; i < 4; ++i) { o[i] = 0; m[i] = NEGB; l[i] = 0.f; }

  const bf16x8* kch = (const bf16x8*)k + (size_t)b * T_SEQ * 8;
  const unsigned short* vch = vTb + (size_t)b * 131072;

  // balanced contiguous tile-chunks over this block's NT key-tiles
  int NT = tile + 1;
  int qn = NT >> 2, rem = NT & 3;
  int start = j * qn + (j < rem ? j : rem);
  int end = start + qn + (j < rem ? 1 : 0);
  int capw = ((t_base + 15) >> 5) + 1;
  if (end > capw) end = capw;

  for (int tt = start; tt < end; ++tt) {
    int s0 = tt * 32;
    f32x4 sa0, sa1;
    sa0 = 0; sa1 = 0;
    bf16x8 kb00 = kch[(size_t)(s0 + l15) * 8 + g];
    bf16x8 kb01 = kch[(size_t)(s0 + l15) * 8 + 4 + g];
    bf16x8 kb10 = kch[(size_t)(s0 + 16 + l15) * 8 + g];
    bf16x8 kb11 = kch[(size_t)(s0 + 16 + l15) * 8 + 4 + g];
    sa0 = mfma16(aq0, kb00, sa0);
    sa0 = mfma16(aq1, kb01, sa0);
    sa1 = mfma16(aq0, kb10, sa1);
    sa1 = mfma16(aq1, kb11, sa1);
#pragma unroll
    for (int vv = 0; vv < 4; ++vv) {
      int t = t_base + g * 4 + vv;
      float v0 = (s0 + l15 <= t) ? sa0[vv] : NEGB;
      float v1 = (s0 + 16 + l15 <= t) ? sa1[vv] : NEGB;
      float rm = fmaxf(v0, v1);
#pragma unroll
      for (int off = 8; off >= 1; off >>= 1)
        rm = fmaxf(rm, __shfl_xor(rm, off));
      float mn = fmaxf(m[vv], rm);
      float corr = __expf(m[vv] - mn);
      float p0 = (v0 == NEGB) ? 0.f : __expf(v0 - mn);  // all-masked tile guard
      float p1 = (v1 == NEGB) ? 0.f : __expf(v1 - mn);
      float rs = p0 + p1;
#pragma unroll
      for (int off = 8; off >= 1; off >>= 1) rs += __shfl_xor(rs, off);
      l[vv] = l[vv] * corr + rs;
      m[vv] = mn;
#pragma unroll
      for (int nt = 0; nt < 4; ++nt) o[nt][vv] *= corr;
      pL[w][g * 4 + vv][l15] = f2bf(p0);
      pL[w][g * 4 + vv][16 + l15] = f2bf(p1);
    }
    bf16x8 ap = *(const bf16x8*)&pL[w][l15][g * 8];
#pragma unroll
    for (int nt = 0; nt < 4; ++nt) {
      bf16x8 bv =
          *(const bf16x8*)&vch[((size_t)(tt * 64 + nt * 16 + l15)) * 32 + g * 8];
      o[nt] = mfma16(ap, bv, o[nt]);
    }
  }

  __syncthreads();
#pragma unroll
  for (int nt = 0; nt < 4; ++nt)
#pragma unroll
    for (int vv = 0; vv < 4; ++vv)
      oP[j][r][g * 4 + vv][nt * 16 + l15] = f2bf(o[nt][vv]);
  if (l15 == 0) {
#pragma unroll
    for (int vv = 0; vv < 4; ++vv) {
      mP[j][r][g * 4 + vv] = m[vv];
      lP[j][r][g * 4 + vv] = l[vv];
    }
  }
  __syncthreads();

  if (w < 2) {  // merge wave r=w: 16 rows x 64 cols, 4-way j-merge
    int len = lengths[b];
#pragma unroll 4
    for (int row = 0; row < 16; ++row) {
      float m0 = mP[0][w][row], m1 = mP[1][w][row];
      float m2 = mP[2][w][row], m3 = mP[3][w][row];
      float ms = fmaxf(fmaxf(m0, m1), fmaxf(m2, m3));
      float e0 = __expf(m0 - ms), e1 = __expf(m1 - ms);
      float e2 = __expf(m2 - ms), e3 = __expf(m3 - ms);
      float ls = lP[0][w][row] * e0 + lP[1][w][row] * e1 +
                 lP[2][w][row] * e2 + lP[3][w][row] * e3;
      float ov = bf2f(oP[0][w][row][lane]) * e0 +
                 bf2f(oP[1][w][row][lane]) * e1 +
                 bf2f(oP[2][w][row][lane]) * e2 +
                 bf2f(oP[3][w][row][lane]) * e3;
      float val = ov / ls;
      int t = t0 + w * 16 + row;
      if (t >= len) val = vmean[b * 64 + lane];  // padded query row -> mean(v)
      Out[((size_t)b * T_SEQ + t) * 64 + lane] = val;
    }
  }
}

extern "C" void kernel_launch(void* const* d_in, const int* in_sizes, int n_in,
                              void* d_out, int out_size, void* d_ws,
                              size_t ws_size, hipStream_t stream) {
  const float* V = (const float*)d_in[0];
  const float* K = (const float*)d_in[1];
  const float* Q = (const float*)d_in[2];
  const float* Wq = (const float*)d_in[3];
  const float* Wk = (const float*)d_in[4];
  const float* Wv = (const float*)d_in[5];
  const unsigned char* mask = (const unsigned char*)d_in[6];
  float* O = (float*)d_out;
  char* ws = (char*)d_ws;

  unsigned short* wt = (unsigned short*)(ws);                        // 384 KiB
  unsigned short* qb = (unsigned short*)(ws + 393216);               // 2 MiB
  unsigned short* kb = (unsigned short*)(ws + 393216 + 2097152);     // 2 MiB
  unsigned short* vTb = (unsigned short*)(ws + 393216 + 2 * 2097152);// 2 MiB
  float* vmean = (float*)(ws + 393216 + 3 * 2097152);                // 2 KiB
  int* lengths = (int*)(ws + 393216 + 3 * 2097152 + 2048);
  int* flag = lengths + 8;

  detect_k<<<1, 256, 0, stream>>>(mask, flag);
  lengths_k<<<NB, 256, 0, stream>>>(mask, flag, lengths);
  wt_k<<<768, 256, 0, stream>>>(Wq, Wk, Wv, wt);
  proj_k<<<dim3(256, 3), 512, 0, stream>>>(Q, K, V, wt, qb, kb, vTb);
  vmean_k<<<NB, 256, 0, stream>>>(vTb, vmean);
  attn_k<<<512, 512, 0, stream>>>(qb, kb, vTb, vmean, lengths, O);
}